// Round 5
// baseline (213.925 us; speedup 1.0000x reference)
//
#include <hip/hip_runtime.h>

typedef __bf16 bf16_t;
typedef __bf16 bf16x8 __attribute__((ext_vector_type(8)));
typedef __bf16 bf16x4 __attribute__((ext_vector_type(4)));
typedef float f32x4 __attribute__((ext_vector_type(4)));
typedef unsigned short u16x8 __attribute__((ext_vector_type(8)));

#define AS1C(p) ((const __attribute__((address_space(1))) void*)(p))
#define AS3(p) ((__attribute__((address_space(3))) void*)(p))

__device__ __forceinline__ unsigned short f2b_rne(float f) {
  union { float f; unsigned u; } x; x.f = f;
  unsigned u = x.u;
  u += 0x7fffu + ((u >> 16) & 1u);
  return (unsigned short)(u >> 16);
}

__device__ __forceinline__ float fast_exp2(float x) {
  return __builtin_amdgcn_exp2f(x);
}

// ---------------- cast f32 -> bf16 (vectorized, 8 elts/thread) ----------------
__global__ __launch_bounds__(256) void cast_f32_bf16(const float* __restrict__ in,
                                                     unsigned short* __restrict__ out,
                                                     int n) {
  int i = (blockIdx.x * 256 + threadIdx.x) * 8;
  if (i >= n) return;
  const float4* p = reinterpret_cast<const float4*>(in + i);
  float4 a = p[0], b = p[1];
  u16x8 o;
  o[0] = f2b_rne(a.x); o[1] = f2b_rne(a.y); o[2] = f2b_rne(a.z); o[3] = f2b_rne(a.w);
  o[4] = f2b_rne(b.x); o[5] = f2b_rne(b.y); o[6] = f2b_rne(b.z); o[7] = f2b_rne(b.w);
  *reinterpret_cast<u16x8*>(out + i) = o;
}

// four 1024x1024 weight casts in one launch; out slots contiguous (2 MB apart)
__global__ __launch_bounds__(256) void cast_w4(const float* __restrict__ w0,
                                               const float* __restrict__ w1,
                                               const float* __restrict__ w2,
                                               const float* __restrict__ w3,
                                               unsigned short* __restrict__ out) {
  const float* in = (blockIdx.y == 0) ? w0 : (blockIdx.y == 1) ? w1
                  : (blockIdx.y == 2) ? w2 : w3;
  int i = (blockIdx.x * 256 + threadIdx.x) * 8;
  unsigned short* o = out + (size_t)blockIdx.y * (1024u * 1024u);
  const float4* p = reinterpret_cast<const float4*>(in + i);
  float4 a = p[0], b = p[1];
  u16x8 v;
  v[0] = f2b_rne(a.x); v[1] = f2b_rne(a.y); v[2] = f2b_rne(a.z); v[3] = f2b_rne(a.w);
  v[4] = f2b_rne(b.x); v[5] = f2b_rne(b.y); v[6] = f2b_rne(b.z); v[7] = f2b_rne(b.w);
  *reinterpret_cast<u16x8*>(o + i) = v;
}

// ---------------- GEMM: C[M,N] = A[M,K] * B[N,K]^T  (m97-style 128x128 tile) ----------------
// A row stride = lda (elements); scale applied to columns n0 < qlim
template <int OUT_F32>
__global__ __launch_bounds__(256) void gemm_bt(const bf16_t* __restrict__ A,
                                               const bf16_t* __restrict__ Bm,
                                               void* __restrict__ C,
                                               int M, int N, int K, int lda,
                                               float scale, int qlim) {
  __shared__ bf16_t As[128 * 32];
  __shared__ bf16_t Bs[128 * 32];
  const int tid = threadIdx.x;
  const int lane = tid & 63, wave = tid >> 6;
  const int wm = wave >> 1, wn = wave & 1;
  const int r = lane & 15, kg = lane >> 4;
  const int m0 = blockIdx.y * 128, n0 = blockIdx.x * 128;
  const float sc = (n0 < qlim) ? scale : 1.0f;
  f32x4 acc[4][4] = {};
  const size_t abase = (size_t)m0 * lda;
  const size_t bbase = (size_t)n0 * K;
  for (int k0 = 0; k0 < K; k0 += 32) {
#pragma unroll
    for (int c = 0; c < 2; ++c) {
      int e = (c * 256 + tid) * 8;
      int rr = e >> 5, cc = e & 31;
      __builtin_amdgcn_global_load_lds(AS1C(A + abase + (size_t)rr * lda + k0 + cc),
                                       AS3(As + (c * 256 + wave * 64) * 8), 16, 0, 0);
      __builtin_amdgcn_global_load_lds(AS1C(Bm + bbase + (size_t)rr * K + k0 + cc),
                                       AS3(Bs + (c * 256 + wave * 64) * 8), 16, 0, 0);
    }
    __syncthreads();
    bf16x8 af[4], bfr[4];
#pragma unroll
    for (int t = 0; t < 4; ++t) {
      af[t]  = *reinterpret_cast<const bf16x8*>(As + (wm * 64 + t * 16 + r) * 32 + kg * 8);
      bfr[t] = *reinterpret_cast<const bf16x8*>(Bs + (wn * 64 + t * 16 + r) * 32 + kg * 8);
    }
    __builtin_amdgcn_s_setprio(1);
#pragma unroll
    for (int i = 0; i < 4; ++i)
#pragma unroll
      for (int j = 0; j < 4; ++j)
        acc[i][j] = __builtin_amdgcn_mfma_f32_16x16x32_bf16(af[i], bfr[j], acc[i][j], 0, 0, 0);
    __builtin_amdgcn_s_setprio(0);
    __syncthreads();
  }
#pragma unroll
  for (int i = 0; i < 4; ++i) {
#pragma unroll
    for (int j = 0; j < 4; ++j) {
      const int mb = m0 + wm * 64 + i * 16 + kg * 4;
      const int nc = n0 + wn * 64 + j * 16 + r;
#pragma unroll
      for (int v = 0; v < 4; ++v) {
        float val = acc[i][j][v] * sc;
        size_t idx = (size_t)(mb + v) * N + nc;
        if (OUT_F32) reinterpret_cast<float*>(C)[idx] = val;
        else reinterpret_cast<unsigned short*>(C)[idx] = f2b_rne(val);
      }
    }
  }
}

// ---------------- V transpose: qkv V-columns [B*S][3072](+2048) -> VT [B*H][64][2048] ----------------
__global__ __launch_bounds__(256) void transpose_v(const bf16_t* __restrict__ qkv,
                                                   bf16_t* __restrict__ vt) {
  __shared__ bf16_t Vs[64 * 72];
  const int t = threadIdx.x;
  const int s0 = blockIdx.x * 64;
  const int bh = blockIdx.y;
  const int b = bh >> 4, h = bh & 15;
  const size_t in_base = ((size_t)b * 2048 + s0) * 3072 + 2048 + h * 64;
#pragma unroll
  for (int c = 0; c < 2; ++c) {
    int chunk = c * 256 + t;
    int ss = chunk >> 3, dd = (chunk & 7) * 8;
    bf16x8 v = *reinterpret_cast<const bf16x8*>(qkv + in_base + (size_t)ss * 3072 + dd);
    *reinterpret_cast<bf16x8*>(Vs + ss * 72 + dd) = v;
  }
  __syncthreads();
  const size_t out_base = (size_t)bh * 64 * 2048 + s0;
#pragma unroll
  for (int c = 0; c < 2; ++c) {
    int chunk = c * 256 + t;
    int dd = chunk >> 3, ss = (chunk & 7) * 8;
    bf16x8 o;
#pragma unroll
    for (int j = 0; j < 8; ++j) o[j] = Vs[(ss + j) * 72 + dd];
    *reinterpret_cast<bf16x8*>(vt + out_base + (size_t)dd * 2048 + ss) = o;
  }
}

// ---------------- causal flash attention ----------------
// Q,K from fused qkv [B*S][3072] (Q cols scaled by 1/sqrt(dk)*log2(e)); V^T from VT [B*H][64][2048].
// O written in-place into qkv Q columns.  Softmax runs in exp2 domain with defer-max (THR=8).
// grid (16, 64), 512 thr = 8 waves, 128 q-rows per block, one q-tile per block.
// XCD mapping: dispatch XCD = blockIdx.x&7; we assign heads 8x..8x+7 to XCD x so each XCD's
// K/V working set = 8 heads x 512 KB = 4 MB = its L2.  Longest q-tiles dispatch first (LPT).
__global__ __launch_bounds__(512) void flash_attn(const bf16_t* __restrict__ QKV,
                                                  const bf16_t* __restrict__ VT,
                                                  unsigned short* __restrict__ O,
                                                  int ostride) {
  __shared__ bf16_t Ks[64 * 72];       // K tile [n][dk]
  __shared__ bf16_t Vts[64 * 72];      // V^T tile [d][n]
  __shared__ bf16_t Pl[8][16 * 72];    // per-wave P in A-frag layout [q][n]
  const int tid = threadIdx.x;
  const int lane = tid & 63, wave = tid >> 6;
  const int r = lane & 15, kg = lane >> 4;
  const int xcd = blockIdx.x & 7;
  const int bh = xcd * 8 + (blockIdx.y & 7);
  const int qt = 15 - ((blockIdx.x >> 3) * 8 + (blockIdx.y >> 3));
  const int b = bh >> 4, h = bh & 15;
  const size_t qkv_row0 = (size_t)b * 2048 * 3072;
  const int qcol = h * 64, kcol = 1024 + h * 64;
  const size_t vt_base = (size_t)bh * 64 * 2048;
  const size_t o_row0 = (size_t)b * 2048 * ostride;
  const int ocol = h * 64;
  const int srr = tid >> 3, scc = (tid & 7) * 8;  // staging: 512 thr x 16B = one 64x64 bf16 tile

  const int q0 = qt * 128;
  const int qrow = q0 + wave * 16 + r;           // this lane's softmax row
  const int tmax_w = (q0 + wave * 16 + 15) >> 6; // wave's last (diagonal) tile
  const int ntiles = qt * 2 + 2;

  const size_t qoff = qkv_row0 + (size_t)qrow * 3072 + qcol;
  bf16x8 qf0 = *reinterpret_cast<const bf16x8*>(QKV + qoff + kg * 8);
  bf16x8 qf1 = *reinterpret_cast<const bf16x8*>(QKV + qoff + 32 + kg * 8);

  f32x4 oacc[4] = {};
  float m_run = -3e30f, l_run = 0.f;

  // prologue: tile 0 into regs (loads always issued one tile ahead of compute)
  bf16x8 gk = *reinterpret_cast<const bf16x8*>(QKV + qkv_row0 + (size_t)srr * 3072 + kcol + scc);
  bf16x8 gv = *reinterpret_cast<const bf16x8*>(VT + vt_base + (size_t)srr * 2048 + scc);

  for (int t = 0; t < ntiles; ++t) {
    __syncthreads();  // previous tile's LDS readers done
    *reinterpret_cast<bf16x8*>(Ks + srr * 72 + scc) = gk;
    *reinterpret_cast<bf16x8*>(Vts + srr * 72 + scc) = gv;
    __syncthreads();
    if (t + 1 < ntiles) {  // prefetch next tile; HBM latency hides under compute below
      const int kv1 = (t + 1) * 64;
      gk = *reinterpret_cast<const bf16x8*>(QKV + qkv_row0 + (size_t)(kv1 + srr) * 3072 + kcol + scc);
      gv = *reinterpret_cast<const bf16x8*>(VT + vt_base + (size_t)srr * 2048 + kv1 + scc);
    }
    if (t > tmax_w) continue;  // fully masked for this wave (no barriers below)

    const int kv0 = t * 64;
    // S^T = mfma(K, Q): out col = q (=r), row = k-local (kg*4+v) -> row-softmax is lane-local
    float vals[16];
#pragma unroll
    for (int nt = 0; nt < 4; ++nt) {
      bf16x8 kf0 = *reinterpret_cast<const bf16x8*>(Ks + (nt * 16 + r) * 72 + kg * 8);
      bf16x8 kf1 = *reinterpret_cast<const bf16x8*>(Ks + (nt * 16 + r) * 72 + 32 + kg * 8);
      f32x4 s = {};
      __builtin_amdgcn_s_setprio(1);
      s = __builtin_amdgcn_mfma_f32_16x16x32_bf16(kf0, qf0, s, 0, 0, 0);
      s = __builtin_amdgcn_mfma_f32_16x16x32_bf16(kf1, qf1, s, 0, 0, 0);
      __builtin_amdgcn_s_setprio(0);
#pragma unroll
      for (int v = 0; v < 4; ++v) vals[nt * 4 + v] = s[v];
    }
    if (t == tmax_w) {  // diagonal tile: mask k > q
#pragma unroll
      for (int nt = 0; nt < 4; ++nt)
#pragma unroll
        for (int v = 0; v < 4; ++v)
          if (kv0 + nt * 16 + kg * 4 + v > qrow) vals[nt * 4 + v] = -3e30f;
    }
    // partial row max over this lane's 16 scores (max3-friendly tree)
    float a0 = fmaxf(fmaxf(vals[0], vals[1]), vals[2]);
    float a1 = fmaxf(fmaxf(vals[3], vals[4]), vals[5]);
    float a2 = fmaxf(fmaxf(vals[6], vals[7]), vals[8]);
    float a3 = fmaxf(fmaxf(vals[9], vals[10]), vals[11]);
    float a4 = fmaxf(fmaxf(vals[12], vals[13]), vals[14]);
    float pmax = fmaxf(fmaxf(fmaxf(a0, a1), fmaxf(a2, a3)), fmaxf(a4, vals[15]));
    pmax = fmaxf(pmax, __shfl_xor(pmax, 16));
    pmax = fmaxf(pmax, __shfl_xor(pmax, 32));
    // defer-max: only rescale when some row grew past THR=8 (P bounded by 2^8)
    if (!__all(pmax <= m_run + 8.0f)) {
      const float m_new = fmaxf(m_run, pmax);
      const float alpha = fast_exp2(m_run - m_new);
      l_run *= alpha;
      f32x4 al;
#pragma unroll
      for (int v = 0; v < 4; ++v) al[v] = __shfl(alpha, kg * 4 + v);
#pragma unroll
      for (int dt = 0; dt < 4; ++dt)
#pragma unroll
        for (int v = 0; v < 4; ++v) oacc[dt][v] *= al[v];
      m_run = m_new;
    }
    float psum = 0.f;
#pragma unroll
    for (int ii = 0; ii < 16; ++ii) {
      float p = fast_exp2(vals[ii] - m_run);
      vals[ii] = p;
      psum += p;
    }
    psum += __shfl_xor(psum, 16);
    psum += __shfl_xor(psum, 32);
    l_run += psum;

    // P -> LDS in A-frag layout (bf16), same-wave write->read (DS in-order within wave)
#pragma unroll
    for (int nt = 0; nt < 4; ++nt) {
      bf16x4 pb;
#pragma unroll
      for (int v = 0; v < 4; ++v) pb[v] = (bf16_t)vals[nt * 4 + v];
      *reinterpret_cast<bf16x4*>(&Pl[wave][r * 72 + nt * 16 + kg * 4]) = pb;
    }
    bf16x8 pa0 = *reinterpret_cast<const bf16x8*>(&Pl[wave][r * 72 + kg * 8]);
    bf16x8 pa1 = *reinterpret_cast<const bf16x8*>(&Pl[wave][r * 72 + 32 + kg * 8]);

    // O += P V : B operand rows = d from Vts
#pragma unroll
    for (int dt = 0; dt < 4; ++dt) {
      bf16x8 vb0 = *reinterpret_cast<const bf16x8*>(Vts + (dt * 16 + r) * 72 + kg * 8);
      bf16x8 vb1 = *reinterpret_cast<const bf16x8*>(Vts + (dt * 16 + r) * 72 + 32 + kg * 8);
      __builtin_amdgcn_s_setprio(1);
      oacc[dt] = __builtin_amdgcn_mfma_f32_16x16x32_bf16(pa0, vb0, oacc[dt], 0, 0, 0);
      oacc[dt] = __builtin_amdgcn_mfma_f32_16x16x32_bf16(pa1, vb1, oacc[dt], 0, 0, 0);
      __builtin_amdgcn_s_setprio(0);
    }
  }

  const float linv = 1.0f / l_run;
  f32x4 il;
#pragma unroll
  for (int v = 0; v < 4; ++v) il[v] = __shfl(linv, kg * 4 + v);
  const size_t orow0 = o_row0 + (size_t)(q0 + wave * 16) * ostride + ocol;
#pragma unroll
  for (int dt = 0; dt < 4; ++dt) {
    const int d = dt * 16 + r;
#pragma unroll
    for (int v = 0; v < 4; ++v)
      O[orow0 + (size_t)(kg * 4 + v) * ostride + d] = f2b_rne(oacc[dt][v] * il[v]);
  }
}

// ---------------- launcher ----------------
extern "C" void kernel_launch(void* const* d_in, const int* in_sizes, int n_in,
                              void* d_out, int out_size, void* d_ws, size_t ws_size,
                              hipStream_t stream) {
  const float* x  = (const float*)d_in[0];
  const float* Wq = (const float*)d_in[1];
  const float* Wk = (const float*)d_in[2];
  const float* Wv = (const float*)d_in[3];
  const float* Wo = (const float*)d_in[4];

  // ws layout (72 MB peak):
  //  phase 1 (casts+QKV GEMM): xb [0,16) | wqb|wkb|wvb|wob [16,24) | qkv [24,72)
  //  phase 2 (transpose/flash): vt [0,16) (xb dead); flash writes O in-place into qkv Q cols
  //  phase 3 (Wo GEMM): qkv as A (lda=3072), wob -> d_out
  char* ws = (char*)d_ws;
  bf16_t* xb  = (bf16_t*)(ws);
  bf16_t* wqb = (bf16_t*)(ws + (16u << 20));
  bf16_t* wob = (bf16_t*)(ws + (22u << 20));
  bf16_t* qkv = (bf16_t*)(ws + (24u << 20));
  bf16_t* vt  = (bf16_t*)(ws);                 // 16 MB, after xb is dead

  const int NX = 4 * 2048 * 1024;
  cast_f32_bf16<<<NX / 2048, 256, 0, stream>>>(x, (unsigned short*)xb, NX);
  cast_w4<<<dim3(512, 4), 256, 0, stream>>>(Wq, Wk, Wv, Wo, (unsigned short*)wqb);

  // fused QKV projection: [8192,1024] x [3072,1024]^T -> [8192,3072]
  // Q columns get 1/sqrt(dk) * log2(e) so flash softmax runs in exp2 domain
  gemm_bt<0><<<dim3(3072 / 128, 8192 / 128), 256, 0, stream>>>(
      xb, wqb, qkv, 8192, 3072, 1024, 1024, 0.18033688011112042f, 1024);

  transpose_v<<<dim3(2048 / 64, 64), 256, 0, stream>>>(qkv, vt);

  flash_attn<<<dim3(16, 64), 512, 0, stream>>>(qkv, vt, (unsigned short*)qkv, 3072);

  // output projection: A = attn output in qkv Q-columns (lda=3072)
  gemm_bt<1><<<dim3(1024 / 128, 8192 / 128), 256, 0, stream>>>(
      qkv, wob, d_out, 8192, 1024, 1024, 3072, 1.0f, 0);
}

// Round 6
// 186.788 us; speedup vs baseline: 1.1453x; 1.1453x over previous
//
#include <hip/hip_runtime.h>

typedef __bf16 bf16_t;
typedef __bf16 bf16x8 __attribute__((ext_vector_type(8)));
typedef __bf16 bf16x4 __attribute__((ext_vector_type(4)));
typedef float f32x4 __attribute__((ext_vector_type(4)));
typedef unsigned short u16x8 __attribute__((ext_vector_type(8)));

#define AS1C(p) ((const __attribute__((address_space(1))) void*)(p))
#define AS3(p) ((__attribute__((address_space(3))) void*)(p))

__device__ __forceinline__ unsigned short f2b_rne(float f) {
  union { float f; unsigned u; } x; x.f = f;
  unsigned u = x.u;
  u += 0x7fffu + ((u >> 16) & 1u);
  return (unsigned short)(u >> 16);
}

__device__ __forceinline__ float fast_exp2(float x) {
  return __builtin_amdgcn_exp2f(x);
}

// ---------------- cast f32 -> bf16 (vectorized, 8 elts/thread) ----------------
__global__ __launch_bounds__(256) void cast_f32_bf16(const float* __restrict__ in,
                                                     unsigned short* __restrict__ out,
                                                     int n) {
  int i = (blockIdx.x * 256 + threadIdx.x) * 8;
  if (i >= n) return;
  const float4* p = reinterpret_cast<const float4*>(in + i);
  float4 a = p[0], b = p[1];
  u16x8 o;
  o[0] = f2b_rne(a.x); o[1] = f2b_rne(a.y); o[2] = f2b_rne(a.z); o[3] = f2b_rne(a.w);
  o[4] = f2b_rne(b.x); o[5] = f2b_rne(b.y); o[6] = f2b_rne(b.z); o[7] = f2b_rne(b.w);
  *reinterpret_cast<u16x8*>(out + i) = o;
}

// four 1024x1024 weight casts in one launch; out slots contiguous (2 MB apart)
__global__ __launch_bounds__(256) void cast_w4(const float* __restrict__ w0,
                                               const float* __restrict__ w1,
                                               const float* __restrict__ w2,
                                               const float* __restrict__ w3,
                                               unsigned short* __restrict__ out) {
  const float* in = (blockIdx.y == 0) ? w0 : (blockIdx.y == 1) ? w1
                  : (blockIdx.y == 2) ? w2 : w3;
  int i = (blockIdx.x * 256 + threadIdx.x) * 8;
  unsigned short* o = out + (size_t)blockIdx.y * (1024u * 1024u);
  const float4* p = reinterpret_cast<const float4*>(in + i);
  float4 a = p[0], b = p[1];
  u16x8 v;
  v[0] = f2b_rne(a.x); v[1] = f2b_rne(a.y); v[2] = f2b_rne(a.z); v[3] = f2b_rne(a.w);
  v[4] = f2b_rne(b.x); v[5] = f2b_rne(b.y); v[6] = f2b_rne(b.z); v[7] = f2b_rne(b.w);
  *reinterpret_cast<u16x8*>(o + i) = v;
}

// ---------------- GEMM: C[M,N] = A[M,K] * B[N,K]^T  (m97-style 128x128 tile) ----------------
// A row stride = lda (elements); scale applied to columns n0 < qlim
template <int OUT_F32>
__global__ __launch_bounds__(256) void gemm_bt(const bf16_t* __restrict__ A,
                                               const bf16_t* __restrict__ Bm,
                                               void* __restrict__ C,
                                               int M, int N, int K, int lda,
                                               float scale, int qlim) {
  __shared__ bf16_t As[128 * 32];
  __shared__ bf16_t Bs[128 * 32];
  const int tid = threadIdx.x;
  const int lane = tid & 63, wave = tid >> 6;
  const int wm = wave >> 1, wn = wave & 1;
  const int r = lane & 15, kg = lane >> 4;
  const int m0 = blockIdx.y * 128, n0 = blockIdx.x * 128;
  const float sc = (n0 < qlim) ? scale : 1.0f;
  f32x4 acc[4][4] = {};
  const size_t abase = (size_t)m0 * lda;
  const size_t bbase = (size_t)n0 * K;
  for (int k0 = 0; k0 < K; k0 += 32) {
#pragma unroll
    for (int c = 0; c < 2; ++c) {
      int e = (c * 256 + tid) * 8;
      int rr = e >> 5, cc = e & 31;
      __builtin_amdgcn_global_load_lds(AS1C(A + abase + (size_t)rr * lda + k0 + cc),
                                       AS3(As + (c * 256 + wave * 64) * 8), 16, 0, 0);
      __builtin_amdgcn_global_load_lds(AS1C(Bm + bbase + (size_t)rr * K + k0 + cc),
                                       AS3(Bs + (c * 256 + wave * 64) * 8), 16, 0, 0);
    }
    __syncthreads();
    bf16x8 af[4], bfr[4];
#pragma unroll
    for (int t = 0; t < 4; ++t) {
      af[t]  = *reinterpret_cast<const bf16x8*>(As + (wm * 64 + t * 16 + r) * 32 + kg * 8);
      bfr[t] = *reinterpret_cast<const bf16x8*>(Bs + (wn * 64 + t * 16 + r) * 32 + kg * 8);
    }
    __builtin_amdgcn_s_setprio(1);
#pragma unroll
    for (int i = 0; i < 4; ++i)
#pragma unroll
      for (int j = 0; j < 4; ++j)
        acc[i][j] = __builtin_amdgcn_mfma_f32_16x16x32_bf16(af[i], bfr[j], acc[i][j], 0, 0, 0);
    __builtin_amdgcn_s_setprio(0);
    __syncthreads();
  }
#pragma unroll
  for (int i = 0; i < 4; ++i) {
#pragma unroll
    for (int j = 0; j < 4; ++j) {
      const int mb = m0 + wm * 64 + i * 16 + kg * 4;
      const int nc = n0 + wn * 64 + j * 16 + r;
#pragma unroll
      for (int v = 0; v < 4; ++v) {
        float val = acc[i][j][v] * sc;
        size_t idx = (size_t)(mb + v) * N + nc;
        if (OUT_F32) reinterpret_cast<float*>(C)[idx] = val;
        else reinterpret_cast<unsigned short*>(C)[idx] = f2b_rne(val);
      }
    }
  }
}

// ---------------- V transpose: qkv V-columns [B*S][3072](+2048) -> VT [B*H][64][2048] ----------------
__global__ __launch_bounds__(256) void transpose_v(const bf16_t* __restrict__ qkv,
                                                   bf16_t* __restrict__ vt) {
  __shared__ bf16_t Vs[64 * 72];
  const int t = threadIdx.x;
  const int s0 = blockIdx.x * 64;
  const int bh = blockIdx.y;
  const int b = bh >> 4, h = bh & 15;
  const size_t in_base = ((size_t)b * 2048 + s0) * 3072 + 2048 + h * 64;
#pragma unroll
  for (int c = 0; c < 2; ++c) {
    int chunk = c * 256 + t;
    int ss = chunk >> 3, dd = (chunk & 7) * 8;
    bf16x8 v = *reinterpret_cast<const bf16x8*>(qkv + in_base + (size_t)ss * 3072 + dd);
    *reinterpret_cast<bf16x8*>(Vs + ss * 72 + dd) = v;
  }
  __syncthreads();
  const size_t out_base = (size_t)bh * 64 * 2048 + s0;
#pragma unroll
  for (int c = 0; c < 2; ++c) {
    int chunk = c * 256 + t;
    int dd = chunk >> 3, ss = (chunk & 7) * 8;
    bf16x8 o;
#pragma unroll
    for (int j = 0; j < 8; ++j) o[j] = Vs[(ss + j) * 72 + dd];
    *reinterpret_cast<bf16x8*>(vt + out_base + (size_t)dd * 2048 + ss) = o;
  }
}

// ---------------- causal flash attention ----------------
// Q,K from fused qkv [B*S][3072] (Q cols pre-scaled by 1/sqrt(dk)*log2(e)); V^T from VT.
// O written in-place into qkv Q columns.  exp2-domain softmax, defer-max THR=8,
// per-lane deferred l-sum (reduced once after the loop).
// grid (64 bh, 8 pair), 512 thr = 8 waves.  Each block does q-tiles {pair, 15-pair} =
// uniform 34 KV-tiles (immune to dispatch order).  XCD = bh%8 -> 8 heads per XCD = 4 MB
// K/V working set = one XCD L2.  K/V LDS double-buffered: ONE barrier per tile.
__global__ __launch_bounds__(512) void flash_attn(const bf16_t* __restrict__ QKV,
                                                  const bf16_t* __restrict__ VT,
                                                  unsigned short* __restrict__ O,
                                                  int ostride) {
  __shared__ bf16_t Ks[2][64 * 72];    // K tile [n][dk], double-buffered
  __shared__ bf16_t Vts[2][64 * 72];   // V^T tile [d][n], double-buffered
  __shared__ bf16_t Pl[8][16 * 72];    // per-wave P in A-frag layout [q][n]
  const int tid = threadIdx.x;
  const int lane = tid & 63, wave = tid >> 6;
  const int r = lane & 15, kg = lane >> 4;
  const int bh = blockIdx.x;           // XCD = bh % 8 (8 heads/XCD)
  const int pair = blockIdx.y;         // 0..7
  const int b = bh >> 4, h = bh & 15;
  const size_t qkv_row0 = (size_t)b * 2048 * 3072;
  const int qcol = h * 64, kcol = 1024 + h * 64;
  const size_t vt_base = (size_t)bh * 64 * 2048;
  const size_t o_row0 = (size_t)b * 2048 * ostride;
  const int ocol = h * 64;
  const int srr = tid >> 3, scc = (tid & 7) * 8;  // staging: 512 thr x 16B = one 64x64 tile

  for (int pass = 0; pass < 2; ++pass) {
    const int qt = pass ? (15 - pair) : pair;
    const int q0 = qt * 128;
    const int qrow = q0 + wave * 16 + r;           // this lane's softmax row
    const int tmax_w = (q0 + wave * 16 + 15) >> 6; // wave's last (diagonal) tile
    const int ntiles = qt * 2 + 2;

    const size_t qoff = qkv_row0 + (size_t)qrow * 3072 + qcol;
    bf16x8 qf0 = *reinterpret_cast<const bf16x8*>(QKV + qoff + kg * 8);
    bf16x8 qf1 = *reinterpret_cast<const bf16x8*>(QKV + qoff + 32 + kg * 8);

    f32x4 oacc[4] = {};
    float m_run = -3e30f, l_lane = 0.f;

    // prologue: tile 0 into regs
    bf16x8 gk = *reinterpret_cast<const bf16x8*>(QKV + qkv_row0 + (size_t)srr * 3072 + kcol + scc);
    bf16x8 gv = *reinterpret_cast<const bf16x8*>(VT + vt_base + (size_t)srr * 2048 + scc);

    for (int t = 0; t < ntiles; ++t) {
      const int buf = t & 1;
      // write current tile into buf; previous readers of buf (tile t-2) finished
      // before barrier(t-1) -> single barrier per tile is safe.
      *reinterpret_cast<bf16x8*>(&Ks[buf][srr * 72 + scc]) = gk;
      *reinterpret_cast<bf16x8*>(&Vts[buf][srr * 72 + scc]) = gv;
      __syncthreads();
      if (t + 1 < ntiles) {  // prefetch next tile; HBM latency hides under compute
        const int kv1 = (t + 1) * 64;
        gk = *reinterpret_cast<const bf16x8*>(QKV + qkv_row0 + (size_t)(kv1 + srr) * 3072 + kcol + scc);
        gv = *reinterpret_cast<const bf16x8*>(VT + vt_base + (size_t)srr * 2048 + kv1 + scc);
      }
      if (t > tmax_w) continue;  // fully masked for this wave (no barriers below)

      const int kv0 = t * 64;
      // S^T = mfma(K, Q): out col = q (=r), row = k-local (kg*4+v) -> softmax lane-local
      float vals[16];
#pragma unroll
      for (int nt = 0; nt < 4; ++nt) {
        bf16x8 kf0 = *reinterpret_cast<const bf16x8*>(&Ks[buf][(nt * 16 + r) * 72 + kg * 8]);
        bf16x8 kf1 = *reinterpret_cast<const bf16x8*>(&Ks[buf][(nt * 16 + r) * 72 + 32 + kg * 8]);
        f32x4 s = {};
        __builtin_amdgcn_s_setprio(1);
        s = __builtin_amdgcn_mfma_f32_16x16x32_bf16(kf0, qf0, s, 0, 0, 0);
        s = __builtin_amdgcn_mfma_f32_16x16x32_bf16(kf1, qf1, s, 0, 0, 0);
        __builtin_amdgcn_s_setprio(0);
#pragma unroll
        for (int v = 0; v < 4; ++v) vals[nt * 4 + v] = s[v];
      }
      if (t == tmax_w) {  // diagonal tile: mask k > q
#pragma unroll
        for (int nt = 0; nt < 4; ++nt)
#pragma unroll
          for (int v = 0; v < 4; ++v)
            if (kv0 + nt * 16 + kg * 4 + v > qrow) vals[nt * 4 + v] = -3e30f;
      }
      // per-lane partial max (max3-friendly tree); cross-lane reduce only when needed
      float a0 = fmaxf(fmaxf(vals[0], vals[1]), vals[2]);
      float a1 = fmaxf(fmaxf(vals[3], vals[4]), vals[5]);
      float a2 = fmaxf(fmaxf(vals[6], vals[7]), vals[8]);
      float a3 = fmaxf(fmaxf(vals[9], vals[10]), vals[11]);
      float a4 = fmaxf(fmaxf(vals[12], vals[13]), vals[14]);
      float pmax = fmaxf(fmaxf(fmaxf(a0, a1), fmaxf(a2, a3)), fmaxf(a4, vals[15]));
      // defer-max: skip rescale while no lane's partial grew past THR=8 (P <= 2^8)
      if (!__all(pmax <= m_run + 8.0f)) {
        pmax = fmaxf(pmax, __shfl_xor(pmax, 16));
        pmax = fmaxf(pmax, __shfl_xor(pmax, 32));
        const float m_new = fmaxf(m_run, pmax);
        const float alpha = fast_exp2(m_run - m_new);
        l_lane *= alpha;
        f32x4 al;
#pragma unroll
        for (int v = 0; v < 4; ++v) al[v] = __shfl(alpha, kg * 4 + v);
#pragma unroll
        for (int dt = 0; dt < 4; ++dt)
#pragma unroll
          for (int v = 0; v < 4; ++v) oacc[dt][v] *= al[v];
        m_run = m_new;
      }
#pragma unroll
      for (int ii = 0; ii < 16; ++ii) {
        float p = fast_exp2(vals[ii] - m_run);
        vals[ii] = p;
        l_lane += p;
      }

      // P -> LDS in A-frag layout (bf16), same-wave write->read
#pragma unroll
      for (int nt = 0; nt < 4; ++nt) {
        bf16x4 pb;
#pragma unroll
        for (int v = 0; v < 4; ++v) pb[v] = (bf16_t)vals[nt * 4 + v];
        *reinterpret_cast<bf16x4*>(&Pl[wave][r * 72 + nt * 16 + kg * 4]) = pb;
      }
      bf16x8 pa0 = *reinterpret_cast<const bf16x8*>(&Pl[wave][r * 72 + kg * 8]);
      bf16x8 pa1 = *reinterpret_cast<const bf16x8*>(&Pl[wave][r * 72 + 32 + kg * 8]);

      // O += P V : B operand rows = d from Vts
#pragma unroll
      for (int dt = 0; dt < 4; ++dt) {
        bf16x8 vb0 = *reinterpret_cast<const bf16x8*>(&Vts[buf][(dt * 16 + r) * 72 + kg * 8]);
        bf16x8 vb1 = *reinterpret_cast<const bf16x8*>(&Vts[buf][(dt * 16 + r) * 72 + 32 + kg * 8]);
        __builtin_amdgcn_s_setprio(1);
        oacc[dt] = __builtin_amdgcn_mfma_f32_16x16x32_bf16(pa0, vb0, oacc[dt], 0, 0, 0);
        oacc[dt] = __builtin_amdgcn_mfma_f32_16x16x32_bf16(pa1, vb1, oacc[dt], 0, 0, 0);
        __builtin_amdgcn_s_setprio(0);
      }
    }

    // deferred l reduction: row sum = lanes {r, r+16, r+32, r+48}
    float l_row = l_lane;
    l_row += __shfl_xor(l_row, 16);
    l_row += __shfl_xor(l_row, 32);
    const float linv = 1.0f / l_row;
    f32x4 il;
#pragma unroll
    for (int v = 0; v < 4; ++v) il[v] = __shfl(linv, kg * 4 + v);
    const size_t orow0 = o_row0 + (size_t)(q0 + wave * 16) * ostride + ocol;
#pragma unroll
    for (int dt = 0; dt < 4; ++dt) {
      const int d = dt * 16 + r;
#pragma unroll
      for (int v = 0; v < 4; ++v)
        O[orow0 + (size_t)(kg * 4 + v) * ostride + d] = f2b_rne(oacc[dt][v] * il[v]);
    }
  }
}

// ---------------- launcher ----------------
extern "C" void kernel_launch(void* const* d_in, const int* in_sizes, int n_in,
                              void* d_out, int out_size, void* d_ws, size_t ws_size,
                              hipStream_t stream) {
  const float* x  = (const float*)d_in[0];
  const float* Wq = (const float*)d_in[1];
  const float* Wk = (const float*)d_in[2];
  const float* Wv = (const float*)d_in[3];
  const float* Wo = (const float*)d_in[4];

  // ws layout (72 MB peak):
  //  phase 1 (casts+QKV GEMM): xb [0,16) | wqb|wkb|wvb|wob [16,24) | qkv [24,72)
  //  phase 2 (transpose/flash): vt [0,16) (xb dead); flash writes O in-place into qkv Q cols
  //  phase 3 (Wo GEMM): qkv as A (lda=3072), wob -> d_out
  char* ws = (char*)d_ws;
  bf16_t* xb  = (bf16_t*)(ws);
  bf16_t* wqb = (bf16_t*)(ws + (16u << 20));
  bf16_t* wob = (bf16_t*)(ws + (22u << 20));
  bf16_t* qkv = (bf16_t*)(ws + (24u << 20));
  bf16_t* vt  = (bf16_t*)(ws);                 // 16 MB, after xb is dead

  const int NX = 4 * 2048 * 1024;
  cast_f32_bf16<<<NX / 2048, 256, 0, stream>>>(x, (unsigned short*)xb, NX);
  cast_w4<<<dim3(512, 4), 256, 0, stream>>>(Wq, Wk, Wv, Wo, (unsigned short*)wqb);

  // fused QKV projection: [8192,1024] x [3072,1024]^T -> [8192,3072]
  // Q columns get 1/sqrt(dk) * log2(e) so flash softmax runs in exp2 domain
  gemm_bt<0><<<dim3(3072 / 128, 8192 / 128), 256, 0, stream>>>(
      xb, wqb, qkv, 8192, 3072, 1024, 1024, 0.18033688011112042f, 1024);

  transpose_v<<<dim3(2048 / 64, 64), 256, 0, stream>>>(qkv, vt);

  flash_attn<<<dim3(64, 8), 512, 0, stream>>>(qkv, vt, (unsigned short*)qkv, 3072);

  // output projection: A = attn output in qkv Q-columns (lda=3072)
  gemm_bt<1><<<dim3(1024 / 128, 8192 / 128), 256, 0, stream>>>(
      qkv, wob, d_out, 8192, 1024, 1024, 3072, 1.0f, 0);
}

// Round 7
// 182.890 us; speedup vs baseline: 1.1697x; 1.0213x over previous
//
#include <hip/hip_runtime.h>

typedef __bf16 bf16_t;
typedef __bf16 bf16x8 __attribute__((ext_vector_type(8)));
typedef __bf16 bf16x4 __attribute__((ext_vector_type(4)));
typedef float f32x4 __attribute__((ext_vector_type(4)));
typedef unsigned short u16x8 __attribute__((ext_vector_type(8)));

#define AS1C(p) ((const __attribute__((address_space(1))) void*)(p))
#define AS3(p) ((__attribute__((address_space(3))) void*)(p))
#define MM(a, b, c) __builtin_amdgcn_mfma_f32_16x16x32_bf16(a, b, c, 0, 0, 0)

__device__ __forceinline__ unsigned short f2b_rne(float f) {
  union { float f; unsigned u; } x; x.f = f;
  unsigned u = x.u;
  u += 0x7fffu + ((u >> 16) & 1u);
  return (unsigned short)(u >> 16);
}

__device__ __forceinline__ float fast_exp2(float x) {
  return __builtin_amdgcn_exp2f(x);
}

// ---------------- cast f32 -> bf16 (vectorized, 8 elts/thread) ----------------
__global__ __launch_bounds__(256) void cast_f32_bf16(const float* __restrict__ in,
                                                     unsigned short* __restrict__ out,
                                                     int n) {
  int i = (blockIdx.x * 256 + threadIdx.x) * 8;
  if (i >= n) return;
  const float4* p = reinterpret_cast<const float4*>(in + i);
  float4 a = p[0], b = p[1];
  u16x8 o;
  o[0] = f2b_rne(a.x); o[1] = f2b_rne(a.y); o[2] = f2b_rne(a.z); o[3] = f2b_rne(a.w);
  o[4] = f2b_rne(b.x); o[5] = f2b_rne(b.y); o[6] = f2b_rne(b.z); o[7] = f2b_rne(b.w);
  *reinterpret_cast<u16x8*>(out + i) = o;
}

// four 1024x1024 weight casts in one launch; out slots contiguous (2 MB apart)
__global__ __launch_bounds__(256) void cast_w4(const float* __restrict__ w0,
                                               const float* __restrict__ w1,
                                               const float* __restrict__ w2,
                                               const float* __restrict__ w3,
                                               unsigned short* __restrict__ out) {
  const float* in = (blockIdx.y == 0) ? w0 : (blockIdx.y == 1) ? w1
                  : (blockIdx.y == 2) ? w2 : w3;
  int i = (blockIdx.x * 256 + threadIdx.x) * 8;
  unsigned short* o = out + (size_t)blockIdx.y * (1024u * 1024u);
  const float4* p = reinterpret_cast<const float4*>(in + i);
  float4 a = p[0], b = p[1];
  u16x8 v;
  v[0] = f2b_rne(a.x); v[1] = f2b_rne(a.y); v[2] = f2b_rne(a.z); v[3] = f2b_rne(a.w);
  v[4] = f2b_rne(b.x); v[5] = f2b_rne(b.y); v[6] = f2b_rne(b.z); v[7] = f2b_rne(b.w);
  *reinterpret_cast<u16x8*>(o + i) = v;
}

// ============ legacy m97-style 128x128 GEMM (kept as fallback, unused) ============
template <int OUT_F32>
__global__ __launch_bounds__(256) void gemm_bt(const bf16_t* __restrict__ A,
                                               const bf16_t* __restrict__ Bm,
                                               void* __restrict__ C,
                                               int M, int N, int K, int lda,
                                               float scale, int qlim) {
  __shared__ bf16_t As[128 * 32];
  __shared__ bf16_t Bs[128 * 32];
  const int tid = threadIdx.x;
  const int lane = tid & 63, wave = tid >> 6;
  const int wm = wave >> 1, wn = wave & 1;
  const int r = lane & 15, kg = lane >> 4;
  const int m0 = blockIdx.y * 128, n0 = blockIdx.x * 128;
  const float sc = (n0 < qlim) ? scale : 1.0f;
  f32x4 acc[4][4] = {};
  const size_t abase = (size_t)m0 * lda;
  const size_t bbase = (size_t)n0 * K;
  for (int k0 = 0; k0 < K; k0 += 32) {
#pragma unroll
    for (int c = 0; c < 2; ++c) {
      int e = (c * 256 + tid) * 8;
      int rr = e >> 5, cc = e & 31;
      __builtin_amdgcn_global_load_lds(AS1C(A + abase + (size_t)rr * lda + k0 + cc),
                                       AS3(As + (c * 256 + wave * 64) * 8), 16, 0, 0);
      __builtin_amdgcn_global_load_lds(AS1C(Bm + bbase + (size_t)rr * K + k0 + cc),
                                       AS3(Bs + (c * 256 + wave * 64) * 8), 16, 0, 0);
    }
    __syncthreads();
    bf16x8 af[4], bfr[4];
#pragma unroll
    for (int t = 0; t < 4; ++t) {
      af[t]  = *reinterpret_cast<const bf16x8*>(As + (wm * 64 + t * 16 + r) * 32 + kg * 8);
      bfr[t] = *reinterpret_cast<const bf16x8*>(Bs + (wn * 64 + t * 16 + r) * 32 + kg * 8);
    }
#pragma unroll
    for (int i = 0; i < 4; ++i)
#pragma unroll
      for (int j = 0; j < 4; ++j)
        acc[i][j] = MM(af[i], bfr[j], acc[i][j]);
    __syncthreads();
  }
#pragma unroll
  for (int i = 0; i < 4; ++i) {
#pragma unroll
    for (int j = 0; j < 4; ++j) {
      const int mb = m0 + wm * 64 + i * 16 + kg * 4;
      const int nc = n0 + wn * 64 + j * 16 + r;
#pragma unroll
      for (int v = 0; v < 4; ++v) {
        float val = acc[i][j][v] * sc;
        size_t idx = (size_t)(mb + v) * N + nc;
        if (OUT_F32) reinterpret_cast<float*>(C)[idx] = val;
        else reinterpret_cast<unsigned short*>(C)[idx] = f2b_rne(val);
      }
    }
  }
}

// ============ 256x256 / BK=64 8-phase GEMM (counted-vmcnt pipeline, T2+T3+T4+T5) ======
// C[M,N] = A[M,K] (row stride lda) * B[N,K]^T.  512 thr = 8 waves (2Mx4N), per-wave out
// 128x64 as 2 A-halves x 2 B-halves (quadrants).  LDS 128 KiB: 2 bufs x (A 256x64 + B 256x64),
// XOR-swizzled (col ^= (row&7)<<3); inverse swizzle applied to per-lane global src (rule #21).
// Schedule (derived race-free): quadrant order (0,0),(0,1),(1,1),(1,0); per-phase stages:
//   ph1: Ah1,Bh0(tile 2n+1->buf1)  ph3: Ah0(2n+2->buf0)  ph4: Bh1(2n+2) +vmcnt(4)
//   ph5: Ah1,Bh0(2n+2)             ph7: Ah0(2n+3->buf1)  ph8: Bh1(2n+3) +vmcnt(4)
// Each stage issues after its region's last read; each landing is guaranteed by a
// vmcnt(4)+barrier that precedes its first reader.  Tail stages clamp to re-write the
// resident tile (identical bytes -> benign).
#define LDSA(bb, ih, il, kk) \
  (*reinterpret_cast<const bf16x8*>(lds + (bb) * 32768 + (ih) * 8192 + aoff##il + acol##kk))
#define LDSB(bb, jh, jl, kk) \
  (*reinterpret_cast<const bf16x8*>(lds + (bb) * 32768 + (jh) * 8192 + boff##jl + acol##kk))
#define STG_A(bb, ih, rd, kt) \
  __builtin_amdgcn_global_load_lds( \
      AS1C(aSrc + (size_t)((ih) * 128 + (rd) * 64) * lda + (kt) * 64), \
      AS3(lds + (bb) * 32768 + ((ih) * 128 + (rd) * 64 + w8) * 64), 16, 0, 0)
#define STG_B(bb, ih, rd, kt) \
  __builtin_amdgcn_global_load_lds( \
      AS1C(bSrc + (size_t)((ih) * 128 + (rd) * 64) * (size_t)K + (kt) * 64), \
      AS3(lds + (bb) * 32768 + 16384 + ((ih) * 128 + (rd) * 64 + w8) * 64), 16, 0, 0)
#define PHASE(bb, qa, qb, RDA, RDB, VMC, ...) do { \
  if (RDA) { A00 = LDSA(bb, qa, 0, 0); A01 = LDSA(bb, qa, 0, 1); \
             A10 = LDSA(bb, qa, 1, 0); A11 = LDSA(bb, qa, 1, 1); \
             A20 = LDSA(bb, qa, 2, 0); A21 = LDSA(bb, qa, 2, 1); \
             A30 = LDSA(bb, qa, 3, 0); A31 = LDSA(bb, qa, 3, 1); } \
  if (RDB) { B00 = LDSB(bb, qb, 0, 0); B01 = LDSB(bb, qb, 0, 1); \
             B10 = LDSB(bb, qb, 1, 0); B11 = LDSB(bb, qb, 1, 1); } \
  __VA_ARGS__; \
  if (VMC) asm volatile("s_waitcnt vmcnt(4)" ::: "memory"); \
  __builtin_amdgcn_s_barrier(); \
  asm volatile("s_waitcnt lgkmcnt(0)" ::: "memory"); \
  __builtin_amdgcn_sched_barrier(0); \
  __builtin_amdgcn_s_setprio(1); \
  acc[qa][0][qb][0] = MM(A01, B01, MM(A00, B00, acc[qa][0][qb][0])); \
  acc[qa][0][qb][1] = MM(A01, B11, MM(A00, B10, acc[qa][0][qb][1])); \
  acc[qa][1][qb][0] = MM(A11, B01, MM(A10, B00, acc[qa][1][qb][0])); \
  acc[qa][1][qb][1] = MM(A11, B11, MM(A10, B10, acc[qa][1][qb][1])); \
  acc[qa][2][qb][0] = MM(A21, B01, MM(A20, B00, acc[qa][2][qb][0])); \
  acc[qa][2][qb][1] = MM(A21, B11, MM(A20, B10, acc[qa][2][qb][1])); \
  acc[qa][3][qb][0] = MM(A31, B01, MM(A30, B00, acc[qa][3][qb][0])); \
  acc[qa][3][qb][1] = MM(A31, B11, MM(A30, B10, acc[qa][3][qb][1])); \
  __builtin_amdgcn_s_setprio(0); \
  __builtin_amdgcn_s_barrier(); \
} while (0)

template <int OUT_F32>
__global__ __launch_bounds__(512, 2) void gemm8(const bf16_t* __restrict__ A,
                                                const bf16_t* __restrict__ Bm,
                                                void* __restrict__ C,
                                                int M, int N, int K, int lda,
                                                float scale, int qlim) {
  extern __shared__ bf16_t lds[];   // 131072 B = 2 bufs x (A 32K + B 32K)
  const int tid = threadIdx.x;
  const int w = tid >> 6, l = tid & 63;
  const int r = l & 15, kg = l >> 4;
  const int wm64 = (w >> 2) * 64, wn32 = (w & 3) * 32;
  const int w8 = w * 8;
  const int rowoff = l >> 3;                      // staging: lane covers row +rowoff
  const int colsw = ((l & 7) ^ (l >> 3)) * 8;     // pre-swizzled source col (inverse XOR)
  const int m0 = blockIdx.y * 256, n0 = blockIdx.x * 256;
  const bf16_t* aSrc = A + (size_t)(m0 + w8 + rowoff) * lda + colsw;
  const bf16_t* bSrc = Bm + (size_t)(n0 + w8 + rowoff) * K + colsw;
  // ds-read offsets (elems): row*64 + ((kk*4+kg)^(r&7))*8
  const int acol0 = (kg ^ (r & 7)) * 8;
  const int acol1 = ((4 + kg) ^ (r & 7)) * 8;
  const int aoff0 = (wm64 + r) * 64;
  const int aoff1 = (wm64 + 16 + r) * 64;
  const int aoff2 = (wm64 + 32 + r) * 64;
  const int aoff3 = (wm64 + 48 + r) * 64;
  const int boff0 = 16384 + (wn32 + r) * 64;
  const int boff1 = 16384 + (wn32 + 16 + r) * 64;

  f32x4 acc[2][4][2][2] = {};
  bf16x8 A00, A01, A10, A11, A20, A21, A30, A31, B00, B01, B10, B11;

  // prologue: tile0 fully + tile1 Ah0/Bh1; full drain once
  STG_A(0, 0, 0, 0); STG_A(0, 0, 1, 0); STG_A(0, 1, 0, 0); STG_A(0, 1, 1, 0);
  STG_B(0, 0, 0, 0); STG_B(0, 0, 1, 0); STG_B(0, 1, 0, 0); STG_B(0, 1, 1, 0);
  STG_A(1, 0, 0, 1); STG_A(1, 0, 1, 1); STG_B(1, 1, 0, 1); STG_B(1, 1, 1, 1);
  asm volatile("s_waitcnt vmcnt(0)" ::: "memory");
  __builtin_amdgcn_s_barrier();

  const int NT = K >> 6;          // K-tiles of 64
  const int NIT = K >> 7;         // iterations (2 tiles each)
  for (int n = 0; n < NIT; ++n) {
    const int kB = 2 * n + 1;
    const int ks2 = (2 * n + 2 < NT) ? 2 * n + 2 : 2 * n;  // clamp -> benign rewrite
    const int ks3 = (2 * n + 3 < NT) ? 2 * n + 3 : kB;
    PHASE(0, 0, 0, 1, 1, 0, STG_A(1, 1, 0, kB); STG_A(1, 1, 1, kB);
                            STG_B(1, 0, 0, kB); STG_B(1, 0, 1, kB));
    PHASE(0, 0, 1, 0, 1, 0, (void)0);
    PHASE(0, 1, 1, 1, 0, 0, STG_A(0, 0, 0, ks2); STG_A(0, 0, 1, ks2));
    PHASE(0, 1, 0, 0, 1, 1, STG_B(0, 1, 0, ks2); STG_B(0, 1, 1, ks2));
    PHASE(1, 0, 0, 1, 1, 0, STG_A(0, 1, 0, ks2); STG_A(0, 1, 1, ks2);
                            STG_B(0, 0, 0, ks2); STG_B(0, 0, 1, ks2));
    PHASE(1, 0, 1, 0, 1, 0, (void)0);
    PHASE(1, 1, 1, 1, 0, 0, STG_A(1, 0, 0, ks3); STG_A(1, 0, 1, ks3));
    PHASE(1, 1, 0, 0, 1, 1, STG_B(1, 1, 0, ks3); STG_B(1, 1, 1, ks3));
  }

  // epilogue: C rows = m0 + qa*128 + wm64 + il*16 + kg*4 + v; cols = n0 + qb*128 + wn32 + jl*16 + r
#pragma unroll
  for (int qa = 0; qa < 2; ++qa)
#pragma unroll
    for (int il = 0; il < 4; ++il)
#pragma unroll
      for (int qb = 0; qb < 2; ++qb)
#pragma unroll
        for (int jl = 0; jl < 2; ++jl) {
          const int row0 = m0 + qa * 128 + wm64 + il * 16 + kg * 4;
          const int col = n0 + qb * 128 + wn32 + jl * 16 + r;
          const float sc = (col < qlim) ? scale : 1.0f;
#pragma unroll
          for (int v = 0; v < 4; ++v) {
            float val = acc[qa][il][qb][jl][v] * sc;
            size_t idx = (size_t)(row0 + v) * N + col;
            if (OUT_F32) reinterpret_cast<float*>(C)[idx] = val;
            else reinterpret_cast<unsigned short*>(C)[idx] = f2b_rne(val);
          }
        }
}

// ---------------- V transpose: qkv V-columns [B*S][3072](+2048) -> VT [B*H][64][2048] ----------------
__global__ __launch_bounds__(256) void transpose_v(const bf16_t* __restrict__ qkv,
                                                   bf16_t* __restrict__ vt) {
  __shared__ bf16_t Vs[64 * 72];
  const int t = threadIdx.x;
  const int s0 = blockIdx.x * 64;
  const int bh = blockIdx.y;
  const int b = bh >> 4, h = bh & 15;
  const size_t in_base = ((size_t)b * 2048 + s0) * 3072 + 2048 + h * 64;
#pragma unroll
  for (int c = 0; c < 2; ++c) {
    int chunk = c * 256 + t;
    int ss = chunk >> 3, dd = (chunk & 7) * 8;
    bf16x8 v = *reinterpret_cast<const bf16x8*>(qkv + in_base + (size_t)ss * 3072 + dd);
    *reinterpret_cast<bf16x8*>(Vs + ss * 72 + dd) = v;
  }
  __syncthreads();
  const size_t out_base = (size_t)bh * 64 * 2048 + s0;
#pragma unroll
  for (int c = 0; c < 2; ++c) {
    int chunk = c * 256 + t;
    int dd = chunk >> 3, ss = (chunk & 7) * 8;
    bf16x8 o;
#pragma unroll
    for (int j = 0; j < 8; ++j) o[j] = Vs[(ss + j) * 72 + dd];
    *reinterpret_cast<bf16x8*>(vt + out_base + (size_t)dd * 2048 + ss) = o;
  }
}

// ---------------- causal flash attention (unchanged from round 6) ----------------
__global__ __launch_bounds__(512) void flash_attn(const bf16_t* __restrict__ QKV,
                                                  const bf16_t* __restrict__ VT,
                                                  unsigned short* __restrict__ O,
                                                  int ostride) {
  __shared__ bf16_t Ks[2][64 * 72];
  __shared__ bf16_t Vts[2][64 * 72];
  __shared__ bf16_t Pl[8][16 * 72];
  const int tid = threadIdx.x;
  const int lane = tid & 63, wave = tid >> 6;
  const int r = lane & 15, kg = lane >> 4;
  const int bh = blockIdx.x;
  const int pair = blockIdx.y;
  const int b = bh >> 4, h = bh & 15;
  const size_t qkv_row0 = (size_t)b * 2048 * 3072;
  const int qcol = h * 64, kcol = 1024 + h * 64;
  const size_t vt_base = (size_t)bh * 64 * 2048;
  const size_t o_row0 = (size_t)b * 2048 * ostride;
  const int ocol = h * 64;
  const int srr = tid >> 3, scc = (tid & 7) * 8;

  for (int pass = 0; pass < 2; ++pass) {
    const int qt = pass ? (15 - pair) : pair;
    const int q0 = qt * 128;
    const int qrow = q0 + wave * 16 + r;
    const int tmax_w = (q0 + wave * 16 + 15) >> 6;
    const int ntiles = qt * 2 + 2;

    const size_t qoff = qkv_row0 + (size_t)qrow * 3072 + qcol;
    bf16x8 qf0 = *reinterpret_cast<const bf16x8*>(QKV + qoff + kg * 8);
    bf16x8 qf1 = *reinterpret_cast<const bf16x8*>(QKV + qoff + 32 + kg * 8);

    f32x4 oacc[4] = {};
    float m_run = -3e30f, l_lane = 0.f;

    bf16x8 gk = *reinterpret_cast<const bf16x8*>(QKV + qkv_row0 + (size_t)srr * 3072 + kcol + scc);
    bf16x8 gv = *reinterpret_cast<const bf16x8*>(VT + vt_base + (size_t)srr * 2048 + scc);

    for (int t = 0; t < ntiles; ++t) {
      const int buf = t & 1;
      *reinterpret_cast<bf16x8*>(&Ks[buf][srr * 72 + scc]) = gk;
      *reinterpret_cast<bf16x8*>(&Vts[buf][srr * 72 + scc]) = gv;
      __syncthreads();
      if (t + 1 < ntiles) {
        const int kv1 = (t + 1) * 64;
        gk = *reinterpret_cast<const bf16x8*>(QKV + qkv_row0 + (size_t)(kv1 + srr) * 3072 + kcol + scc);
        gv = *reinterpret_cast<const bf16x8*>(VT + vt_base + (size_t)srr * 2048 + kv1 + scc);
      }
      if (t > tmax_w) continue;

      const int kv0 = t * 64;
      float vals[16];
#pragma unroll
      for (int nt = 0; nt < 4; ++nt) {
        bf16x8 kf0 = *reinterpret_cast<const bf16x8*>(&Ks[buf][(nt * 16 + r) * 72 + kg * 8]);
        bf16x8 kf1 = *reinterpret_cast<const bf16x8*>(&Ks[buf][(nt * 16 + r) * 72 + 32 + kg * 8]);
        f32x4 s = {};
        __builtin_amdgcn_s_setprio(1);
        s = MM(kf0, qf0, s);
        s = MM(kf1, qf1, s);
        __builtin_amdgcn_s_setprio(0);
#pragma unroll
        for (int v = 0; v < 4; ++v) vals[nt * 4 + v] = s[v];
      }
      if (t == tmax_w) {
#pragma unroll
        for (int nt = 0; nt < 4; ++nt)
#pragma unroll
          for (int v = 0; v < 4; ++v)
            if (kv0 + nt * 16 + kg * 4 + v > qrow) vals[nt * 4 + v] = -3e30f;
      }
      float a0 = fmaxf(fmaxf(vals[0], vals[1]), vals[2]);
      float a1 = fmaxf(fmaxf(vals[3], vals[4]), vals[5]);
      float a2 = fmaxf(fmaxf(vals[6], vals[7]), vals[8]);
      float a3 = fmaxf(fmaxf(vals[9], vals[10]), vals[11]);
      float a4 = fmaxf(fmaxf(vals[12], vals[13]), vals[14]);
      float pmax = fmaxf(fmaxf(fmaxf(a0, a1), fmaxf(a2, a3)), fmaxf(a4, vals[15]));
      if (!__all(pmax <= m_run + 8.0f)) {
        pmax = fmaxf(pmax, __shfl_xor(pmax, 16));
        pmax = fmaxf(pmax, __shfl_xor(pmax, 32));
        const float m_new = fmaxf(m_run, pmax);
        const float alpha = fast_exp2(m_run - m_new);
        l_lane *= alpha;
        f32x4 al;
#pragma unroll
        for (int v = 0; v < 4; ++v) al[v] = __shfl(alpha, kg * 4 + v);
#pragma unroll
        for (int dt = 0; dt < 4; ++dt)
#pragma unroll
          for (int v = 0; v < 4; ++v) oacc[dt][v] *= al[v];
        m_run = m_new;
      }
#pragma unroll
      for (int ii = 0; ii < 16; ++ii) {
        float p = fast_exp2(vals[ii] - m_run);
        vals[ii] = p;
        l_lane += p;
      }
#pragma unroll
      for (int nt = 0; nt < 4; ++nt) {
        bf16x4 pb;
#pragma unroll
        for (int v = 0; v < 4; ++v) pb[v] = (bf16_t)vals[nt * 4 + v];
        *reinterpret_cast<bf16x4*>(&Pl[wave][r * 72 + nt * 16 + kg * 4]) = pb;
      }
      bf16x8 pa0 = *reinterpret_cast<const bf16x8*>(&Pl[wave][r * 72 + kg * 8]);
      bf16x8 pa1 = *reinterpret_cast<const bf16x8*>(&Pl[wave][r * 72 + 32 + kg * 8]);
#pragma unroll
      for (int dt = 0; dt < 4; ++dt) {
        bf16x8 vb0 = *reinterpret_cast<const bf16x8*>(&Vts[buf][(dt * 16 + r) * 72 + kg * 8]);
        bf16x8 vb1 = *reinterpret_cast<const bf16x8*>(&Vts[buf][(dt * 16 + r) * 72 + 32 + kg * 8]);
        __builtin_amdgcn_s_setprio(1);
        oacc[dt] = MM(pa0, vb0, oacc[dt]);
        oacc[dt] = MM(pa1, vb1, oacc[dt]);
        __builtin_amdgcn_s_setprio(0);
      }
    }

    float l_row = l_lane;
    l_row += __shfl_xor(l_row, 16);
    l_row += __shfl_xor(l_row, 32);
    const float linv = 1.0f / l_row;
    f32x4 il;
#pragma unroll
    for (int v = 0; v < 4; ++v) il[v] = __shfl(linv, kg * 4 + v);
    const size_t orow0 = o_row0 + (size_t)(q0 + wave * 16) * ostride + ocol;
#pragma unroll
    for (int dt = 0; dt < 4; ++dt) {
      const int d = dt * 16 + r;
#pragma unroll
      for (int v = 0; v < 4; ++v)
        O[orow0 + (size_t)(kg * 4 + v) * ostride + d] = f2b_rne(oacc[dt][v] * il[v]);
    }
  }
}

// ---------------- launcher ----------------
extern "C" void kernel_launch(void* const* d_in, const int* in_sizes, int n_in,
                              void* d_out, int out_size, void* d_ws, size_t ws_size,
                              hipStream_t stream) {
  const float* x  = (const float*)d_in[0];
  const float* Wq = (const float*)d_in[1];
  const float* Wk = (const float*)d_in[2];
  const float* Wv = (const float*)d_in[3];
  const float* Wo = (const float*)d_in[4];

  // ws layout (72 MB peak):
  //  phase 1 (casts+QKV GEMM): xb [0,16) | wqb|wkb|wvb|wob [16,24) | qkv [24,72)
  //  phase 2 (transpose/flash): vt [0,16) (xb dead); flash writes O in-place into qkv Q cols
  //  phase 3 (Wo GEMM): qkv as A (lda=3072), wob -> d_out
  char* ws = (char*)d_ws;
  bf16_t* xb  = (bf16_t*)(ws);
  bf16_t* wqb = (bf16_t*)(ws + (16u << 20));
  bf16_t* wob = (bf16_t*)(ws + (22u << 20));
  bf16_t* qkv = (bf16_t*)(ws + (24u << 20));
  bf16_t* vt  = (bf16_t*)(ws);

  // allow 128 KiB dynamic LDS for gemm8 (non-stream call; idempotent)
  hipFuncSetAttribute(reinterpret_cast<const void*>(&gemm8<0>),
                      hipFuncAttributeMaxDynamicSharedMemorySize, 131072);
  hipFuncSetAttribute(reinterpret_cast<const void*>(&gemm8<1>),
                      hipFuncAttributeMaxDynamicSharedMemorySize, 131072);

  const int NX = 4 * 2048 * 1024;
  cast_f32_bf16<<<NX / 2048, 256, 0, stream>>>(x, (unsigned short*)xb, NX);
  cast_w4<<<dim3(512, 4), 256, 0, stream>>>(Wq, Wk, Wv, Wo, (unsigned short*)wqb);

  // fused QKV projection: [8192,1024] x [3072,1024]^T -> [8192,3072]
  // Q columns get 1/sqrt(dk) * log2(e) so flash softmax runs in exp2 domain
  gemm8<0><<<dim3(3072 / 256, 8192 / 256), 512, 131072, stream>>>(
      xb, wqb, qkv, 8192, 3072, 1024, 1024, 0.18033688011112042f, 1024);

  transpose_v<<<dim3(2048 / 64, 64), 256, 0, stream>>>(qkv, vt);

  flash_attn<<<dim3(64, 8), 512, 0, stream>>>(qkv, vt, (unsigned short*)qkv, 3072);

  // output projection: A = attn output in qkv Q-columns (lda=3072)
  gemm8<1><<<dim3(1024 / 256, 8192 / 256), 512, 131072, stream>>>(
      qkv, wob, d_out, 8192, 1024, 1024, 3072, 1.0f, 0);
}